// Round 16
// baseline (184.924 us; speedup 1.0000x reference)
//
#include <hip/hip_runtime.h>
#include <hip/hip_bf16.h>
#include <math.h>

// Problem constants
#define S 64
#define F 10
#define K 7
#define D 512
#define HH 196   // H*H = 14*14
#define DT 128
#define NF (S*F)          // 640
#define NROWS_V (S*F*K)   // 4480
#define NROWS_A (S*K)     // 448
#define NOUT (S*K*F)      // 4480
#define MLP_BLK_A (NROWS_A / 16)   // 28
#define MLP_BLK_V (NROWS_V / 16)   // 280
#define FG_BLKS (NF * 2)           // 1280
#define CONV_BLKS 864

// Measurement: fg path repeats 4x (identical writes, zoff==0 runtime-opaque)
// so the fused dispatch exceeds the ~150us poison fills and surfaces in
// rocprof top-5 with counters. Strip next round.
#define FG_REPS 4

typedef short bf16x8 __attribute__((ext_vector_type(8)));
typedef float f32x4 __attribute__((ext_vector_type(4)));

__device__ __forceinline__ unsigned short bfc(float x) {
  __hip_bfloat16 h = __float2bfloat16(x);
  return *reinterpret_cast<unsigned short*>(&h);
}

// ---------------------------------------------------------------------------
// Kernel 1 (v11 + reps): fused fg-MFMA + input-conversion dispatch.
// Blocks [0,1280): fg (rep-looped). Blocks [1280,2144): conv (once).
// ---------------------------------------------------------------------------
__global__ __launch_bounds__(256) void fgconv_kernel(
    const float* __restrict__ feat, const float* __restrict__ cam,
    unsigned short* __restrict__ fgb,
    const float* __restrict__ feat_a,
    const float* __restrict__ W1a, const float* __restrict__ W1v,
    const float* __restrict__ W2a, const float* __restrict__ W2v,
    unsigned short* __restrict__ XaB,
    unsigned short* __restrict__ W1aT, unsigned short* __restrict__ W1vT,
    unsigned short* __restrict__ W2aT, unsigned short* __restrict__ W2vT,
    int reps, size_t zoff) {
  const int t = threadIdx.x;

  if (blockIdx.x >= FG_BLKS) {
    // ---------------- conv path (executes once) ----------------
    const int b = blockIdx.x - FG_BLKS;
    if (b < 224) {  // feat_a: 57344 float4
      const int o = b * 256 + t;
      const float4 v = reinterpret_cast<const float4*>(feat_a)[o];
      unsigned short s0 = bfc(v.x), s1 = bfc(v.y), s2 = bfc(v.z), s3 = bfc(v.w);
      uint2 pk;
      pk.x = ((unsigned)s1 << 16) | s0;
      pk.y = ((unsigned)s3 << 16) | s2;
      reinterpret_cast<uint2*>(XaB)[o] = pk;
    } else if (b < 480) {
      const int o = (b - 224) * 256 + t;
      const int j = o >> 9, d = o & 511;
      W1aT[o] = bfc(W1a[d * DT + j]);
    } else if (b < 736) {
      const int o = (b - 480) * 256 + t;
      const int j = o >> 9, d = o & 511;
      W1vT[o] = bfc(W1v[d * DT + j]);
    } else if (b < 800) {
      const int o = (b - 736) * 256 + t;
      const int j = o >> 7, d = o & 127;
      W2aT[o] = bfc(W2a[d * DT + j]);
    } else {
      const int o = (b - 800) * 256 + t;
      const int j = o >> 7, d = o & 127;
      W2vT[o] = bfc(W2v[d * DT + j]);
    }
    return;
  }

  // ---------------- fg path (rep-looped for measurement) ----------------
  const int lane = t & 63;
  const int w = t >> 6;
  const int col = lane & 15;
  const int kg = lane >> 4;
  const int n = blockIdx.x >> 1;
  const int half = blockIdx.x & 1;
  const int c0blk = half * 256;

  for (int r = 0; r < reps; ++r) {
    const float* featn = feat + r * zoff + ((size_t)n * D + c0blk) * HH;
    const float* camn = cam + r * zoff + (size_t)n * K * HH;

    bf16x8 bs[7];
    {
      const float* crow = camn + col * HH;
#pragma unroll
      for (int s = 0; s < 7; ++s) {
        float v0 = 0.f, v1 = 0.f, v2 = 0.f, v3 = 0.f;
        float v4 = 0.f, v5 = 0.f, v6 = 0.f, v7 = 0.f;
        if (col < 7) {
          if (s < 6) {
            const float4 lo = *reinterpret_cast<const float4*>(crow + s * 32 + kg * 8);
            const float4 hi = *reinterpret_cast<const float4*>(crow + s * 32 + kg * 8 + 4);
            v0 = lo.x; v1 = lo.y; v2 = lo.z; v3 = lo.w;
            v4 = hi.x; v5 = hi.y; v6 = hi.z; v7 = hi.w;
          } else if (kg == 0) {
            const float4 lo = *reinterpret_cast<const float4*>(crow + 192);
            v0 = lo.x; v1 = lo.y; v2 = lo.z; v3 = lo.w;
          }
        }
        bs[s][0] = bfc(v0); bs[s][1] = bfc(v1); bs[s][2] = bfc(v2); bs[s][3] = bfc(v3);
        bs[s][4] = bfc(v4); bs[s][5] = bfc(v5); bs[s][6] = bfc(v6); bs[s][7] = bfc(v7);
      }
    }

    float invc = 0.f;
#pragma unroll
    for (int k = 0; k < K; ++k) {
      float4 cv = (lane < 49)
                      ? *reinterpret_cast<const float4*>(camn + k * HH + 4 * lane)
                      : make_float4(0.f, 0.f, 0.f, 0.f);
      float s = cv.x + cv.y + cv.z + cv.w;
#pragma unroll
      for (int m = 32; m >= 1; m >>= 1) s += __shfl_xor(s, m, 64);
      const float iv = 1.0f / (s + 1e-10f);
      if (col == k) invc = iv;
    }

    unsigned short* fgn = fgb + (size_t)n * K * D;

#pragma unroll
    for (int mt = 0; mt < 4; ++mt) {
      const int chl = (w * 4 + mt) * 16 + col;
      const float* rowp = featn + (size_t)chl * HH;

      f32x4 acc = {0.f, 0.f, 0.f, 0.f};
#pragma unroll
      for (int s = 0; s < 7; ++s) {
        float v0 = 0.f, v1 = 0.f, v2 = 0.f, v3 = 0.f;
        float v4 = 0.f, v5 = 0.f, v6 = 0.f, v7 = 0.f;
        if (s < 6) {
          const float4 lo = *reinterpret_cast<const float4*>(rowp + s * 32 + kg * 8);
          const float4 hi = *reinterpret_cast<const float4*>(rowp + s * 32 + kg * 8 + 4);
          v0 = lo.x; v1 = lo.y; v2 = lo.z; v3 = lo.w;
          v4 = hi.x; v5 = hi.y; v6 = hi.z; v7 = hi.w;
        } else if (kg == 0) {
          const float4 lo = *reinterpret_cast<const float4*>(rowp + 192);
          v0 = lo.x; v1 = lo.y; v2 = lo.z; v3 = lo.w;
        }
        bf16x8 a;
        a[0] = bfc(v0); a[1] = bfc(v1); a[2] = bfc(v2); a[3] = bfc(v3);
        a[4] = bfc(v4); a[5] = bfc(v5); a[6] = bfc(v6); a[7] = bfc(v7);
        acc = __builtin_amdgcn_mfma_f32_16x16x32_bf16(a, bs[s], acc, 0, 0, 0);
      }

      if (col < 7) {
        uint2 pk;
        pk.x = ((unsigned)bfc(acc[1] * invc) << 16) | bfc(acc[0] * invc);
        pk.y = ((unsigned)bfc(acc[3] * invc) << 16) | bfc(acc[2] * invc);
        *reinterpret_cast<uint2*>(
            fgn + (size_t)col * D + c0blk + (w * 4 + mt) * 16 + kg * 4) = pk;
      }
    }
  }
}

// ---------------------------------------------------------------------------
// Kernel 2 (mlp3, MFMA, R14-validated): unchanged.
// ---------------------------------------------------------------------------
__global__ __launch_bounds__(256) void mlp3_kernel(
    const unsigned short* __restrict__ XaB, const unsigned short* __restrict__ XvB,
    const unsigned short* __restrict__ W1aT, const unsigned short* __restrict__ W2aT,
    const float* __restrict__ b1a, const float* __restrict__ b2a,
    const float* __restrict__ ga, const float* __restrict__ bna,
    const unsigned short* __restrict__ W1vT, const unsigned short* __restrict__ W2vT,
    const float* __restrict__ b1v, const float* __restrict__ b2v,
    const float* __restrict__ gv, const float* __restrict__ bnv,
    float* __restrict__ Ta, float* __restrict__ Tv) {
  __shared__ unsigned short hs[16 * 144];

  const int t = threadIdx.x;
  const int lane = t & 63;
  const int w = t >> 6;
  const int c15 = lane & 15;
  const int kg = lane >> 4;
  const int nbase = w * 32;
  const int b = blockIdx.x;

  const unsigned short *XB, *W1T, *W2T;
  const float *b1, *b2, *g, *bn;
  float* out;
  int r0;
  if (b < MLP_BLK_A) {
    XB = XaB; W1T = W1aT; W2T = W2aT; b1 = b1a; b2 = b2a; g = ga; bn = bna;
    out = Ta; r0 = b * 16;
  } else {
    XB = XvB; W1T = W1vT; W2T = W2vT; b1 = b1v; b2 = b2v; g = gv; bn = bnv;
    out = Tv; r0 = (b - MLP_BLK_A) * 16;
  }

  const unsigned short* xp = XB + (size_t)(r0 + c15) * D + kg * 8;
  const unsigned short* wp0 = W1T + (size_t)(nbase + c15) * D + kg * 8;
  const unsigned short* wp1 = W1T + (size_t)(nbase + 16 + c15) * D + kg * 8;

  f32x4 acc0 = {0.f, 0.f, 0.f, 0.f};
  f32x4 acc1 = {0.f, 0.f, 0.f, 0.f};
#pragma unroll
  for (int s = 0; s < 16; ++s) {
    const bf16x8 a = *reinterpret_cast<const bf16x8*>(xp + s * 32);
    const bf16x8 w0 = *reinterpret_cast<const bf16x8*>(wp0 + s * 32);
    const bf16x8 w1 = *reinterpret_cast<const bf16x8*>(wp1 + s * 32);
    acc0 = __builtin_amdgcn_mfma_f32_16x16x32_bf16(a, w0, acc0, 0, 0, 0);
    acc1 = __builtin_amdgcn_mfma_f32_16x16x32_bf16(a, w1, acc1, 0, 0, 0);
  }

  {
    const float bc0 = b1[nbase + c15];
    const float bc1 = b1[nbase + 16 + c15];
#pragma unroll
    for (int i = 0; i < 4; ++i) {
      const int row = kg * 4 + i;
      hs[row * 144 + nbase + c15] = bfc(fmaxf(acc0[i] + bc0, 0.f));
      hs[row * 144 + nbase + 16 + c15] = bfc(fmaxf(acc1[i] + bc1, 0.f));
    }
  }
  __syncthreads();

  const unsigned short* w2p0 = W2T + (size_t)(nbase + c15) * DT + kg * 8;
  const unsigned short* w2p1 = W2T + (size_t)(nbase + 16 + c15) * DT + kg * 8;
  f32x4 c0 = {0.f, 0.f, 0.f, 0.f};
  f32x4 c1 = {0.f, 0.f, 0.f, 0.f};
#pragma unroll
  for (int s = 0; s < 4; ++s) {
    const bf16x8 a = *reinterpret_cast<const bf16x8*>(hs + c15 * 144 + s * 32 + kg * 8);
    const bf16x8 w0 = *reinterpret_cast<const bf16x8*>(w2p0 + s * 32);
    const bf16x8 w1 = *reinterpret_cast<const bf16x8*>(w2p1 + s * 32);
    c0 = __builtin_amdgcn_mfma_f32_16x16x32_bf16(a, w0, c0, 0, 0, 0);
    c1 = __builtin_amdgcn_mfma_f32_16x16x32_bf16(a, w1, c1, 0, 0, 0);
  }

  {
    const int col0 = nbase + c15;
    const int col1 = nbase + 16 + c15;
    const float b20 = b2[col0], b21 = b2[col1];
    const float g0 = g[col0], g1 = g[col1];
    const float n0 = bn[col0], n1 = bn[col1];
#pragma unroll
    for (int i = 0; i < 4; ++i) {
      const int row = r0 + kg * 4 + i;
      out[(size_t)row * DT + col0] = (c0[i] + b20) * g0 + n0;
      out[(size_t)row * DT + col1] = (c1[i] + b21) * g1 + n1;
    }
  }
}

// ---------------------------------------------------------------------------
// Kernel 3: losses + masks (unchanged).
// ---------------------------------------------------------------------------
__global__ __launch_bounds__(256) void loss_kernel(
    const float* __restrict__ Ta, const float* __restrict__ Tv,
    const float* __restrict__ pred_a, const float* __restrict__ pred_v,
    const int* __restrict__ perm_idx, const int* __restrict__ cls_idx,
    float* __restrict__ out) {
  const int t = threadIdx.x;
  const int sub = t & 31;
  const int idx = blockIdx.x * 8 + (t >> 5);
  const int f = idx % F;
  const int k = (idx / F) % K;
  const int s = idx / (K * F);

  const int p = perm_idx[idx];
  const int c = cls_idx[idx];
  const int rowd = ((s ^ 1) * F + p) * K + c;

  float4 ta = reinterpret_cast<const float4*>(Ta)[(s * K + k) * 32 + sub];
  float4 tv = reinterpret_cast<const float4*>(Tv)[((s * F + f) * K + k) * 32 + sub];
  float4 td = reinterpret_cast<const float4*>(Tv)[rowd * 32 + sub];
  float d1 = 0.f, d2 = 0.f, e;
  e = ta.x - tv.x; d1 += e * e;
  e = ta.y - tv.y; d1 += e * e;
  e = ta.z - tv.z; d1 += e * e;
  e = ta.w - tv.w; d1 += e * e;
  e = ta.x - td.x; d2 += e * e;
  e = ta.y - td.y; d2 += e * e;
  e = ta.z - td.z; d2 += e * e;
  e = ta.w - td.w; d2 += e * e;
#pragma unroll
  for (int m = 16; m >= 1; m >>= 1) {
    d1 += __shfl_xor(d1, m, 64);
    d2 += __shfl_xor(d2, m, 64);
  }
  if (sub == 0) {
    float pa = pred_a[s * K + k];
    bool act = pa > 0.3f;
    int num = (int)floorf(pa * (float)F);
    float pvv = pred_v[(s * F + f) * K + k];
    float sg = 1.0f / (1.0f + expf(-pvv));
    bool mco = act && (sg > 0.3f);
    bool mdi = act && (f < num);
    float lco = d1 * (1.0f / 128.0f);
    float ldi = d2 * (1.0f / 128.0f);
    out[idx] = mco ? lco : 0.0f;
    out[NOUT + idx] = mdi ? ldi : 0.0f;
    out[2 * NOUT + idx] = mco ? 1.0f : 0.0f;
    out[3 * NOUT + idx] = mdi ? 1.0f : 0.0f;
  }
}

extern "C" void kernel_launch(void* const* d_in, const int* in_sizes, int n_in,
                              void* d_out, int out_size, void* d_ws, size_t ws_size,
                              hipStream_t stream) {
  const float* feat_a     = (const float*)d_in[0];
  const float* pred_a     = (const float*)d_in[1];
  const float* feat_v_raw = (const float*)d_in[2];
  const float* pred_v     = (const float*)d_in[3];
  const float* cam        = (const float*)d_in[4];
  const float* W1a = (const float*)d_in[5];
  const float* b1a = (const float*)d_in[6];
  const float* W2a = (const float*)d_in[7];
  const float* b2a = (const float*)d_in[8];
  const float* ga  = (const float*)d_in[9];
  const float* bna = (const float*)d_in[10];
  const float* W1v = (const float*)d_in[11];
  const float* b1v = (const float*)d_in[12];
  const float* W2v = (const float*)d_in[13];
  const float* b2v = (const float*)d_in[14];
  const float* gv  = (const float*)d_in[15];
  const float* bnv = (const float*)d_in[16];
  const int* perm_idx = (const int*)d_in[17];
  const int* cls_idx  = (const int*)d_in[18];
  float* out = (float*)d_out;

  char* w = (char*)d_ws;
  unsigned short* fgb  = (unsigned short*)(w);
  unsigned short* XaB  = (unsigned short*)(w + 4587520);
  unsigned short* W1aT = (unsigned short*)(w + 4587520 + 458752);
  unsigned short* W1vT = (unsigned short*)(w + 4587520 + 458752 + 131072);
  unsigned short* W2aT = (unsigned short*)(w + 4587520 + 458752 + 262144);
  unsigned short* W2vT = (unsigned short*)(w + 4587520 + 458752 + 262144 + 32768);
  float* Ta = (float*)(w + 4587520 + 458752 + 262144 + 65536);
  float* Tv = (float*)(w + 4587520 + 458752 + 262144 + 65536 + 229376);

  fgconv_kernel<<<FG_BLKS + CONV_BLKS, 256, 0, stream>>>(
      feat_v_raw, cam, fgb, feat_a, W1a, W1v, W2a, W2v,
      XaB, W1aT, W1vT, W2aT, W2vT, FG_REPS, (size_t)0);
  mlp3_kernel<<<MLP_BLK_A + MLP_BLK_V, 256, 0, stream>>>(
      XaB, fgb, W1aT, W2aT, b1a, b2a, ga, bna,
      W1vT, W2vT, b1v, b2v, gv, bnv, Ta, Tv);
  loss_kernel<<<NOUT / 8, 256, 0, stream>>>(Ta, Tv, pred_a, pred_v, perm_idx,
                                            cls_idx, out);
}

// Round 17
// 88.778 us; speedup vs baseline: 2.0830x; 2.0830x over previous
//
#include <hip/hip_runtime.h>
#include <hip/hip_bf16.h>
#include <math.h>

// Problem constants
#define S 64
#define F 10
#define K 7
#define D 512
#define HH 196   // H*H = 14*14
#define DT 128
#define NF (S*F)          // 640
#define NROWS_V (S*F*K)   // 4480
#define NROWS_A (S*K)     // 448
#define NOUT (S*K*F)      // 4480
#define MLP_BLK_A (NROWS_A / 16)   // 28
#define MLP_BLK_V (NROWS_V / 16)   // 280
#define FG_BLKS (NF * 2)           // 1280
#define CONV_BLKS 864

typedef short bf16x8 __attribute__((ext_vector_type(8)));
typedef float f32x4 __attribute__((ext_vector_type(4)));

__device__ __forceinline__ unsigned short bfc(float x) {
  __hip_bfloat16 h = __float2bfloat16(x);
  return *reinterpret_cast<unsigned short*>(&h);
}

__device__ __forceinline__ bf16x8 cvt8(const float4& lo, const float4& hi) {
  bf16x8 a;
  a[0] = (short)bfc(lo.x); a[1] = (short)bfc(lo.y);
  a[2] = (short)bfc(lo.z); a[3] = (short)bfc(lo.w);
  a[4] = (short)bfc(hi.x); a[5] = (short)bfc(hi.y);
  a[6] = (short)bfc(hi.z); a[7] = (short)bfc(hi.w);
  return a;
}

// ---------------------------------------------------------------------------
// Kernel 1 (v12): fused fg-MFMA + conversions, fg software-pipelined.
// fg path: slab-outer / mt-inner with 4 independent acc chains and a rotating
// prefetch (slab s+1's 8 loads issued before slab s's 4 MFMAs) -> continuous
// load stream per wave instead of burst-stall-compute (R16 counters: 55us,
// VALUBusy 8.9%, latency-bound). Slab-0 preload issued before the bs/invc
// preamble. launch_bounds(256,4) caps VGPR at 128 (16 waves/CU >= measured
// 12 -> no occupancy loss).
// Blocks [1280,2144): conv path (feat_a->bf16, W transposes), unchanged.
// ---------------------------------------------------------------------------
__global__ __launch_bounds__(256, 4) void fgconv_kernel(
    const float* __restrict__ feat, const float* __restrict__ cam,
    unsigned short* __restrict__ fgb,
    const float* __restrict__ feat_a,
    const float* __restrict__ W1a, const float* __restrict__ W1v,
    const float* __restrict__ W2a, const float* __restrict__ W2v,
    unsigned short* __restrict__ XaB,
    unsigned short* __restrict__ W1aT, unsigned short* __restrict__ W1vT,
    unsigned short* __restrict__ W2aT, unsigned short* __restrict__ W2vT) {
  const int t = threadIdx.x;

  if (blockIdx.x >= FG_BLKS) {
    // ---------------- conv path ----------------
    const int b = blockIdx.x - FG_BLKS;
    if (b < 224) {  // feat_a: 57344 float4
      const int o = b * 256 + t;
      const float4 v = reinterpret_cast<const float4*>(feat_a)[o];
      unsigned short s0 = bfc(v.x), s1 = bfc(v.y), s2 = bfc(v.z), s3 = bfc(v.w);
      uint2 pk;
      pk.x = ((unsigned)s1 << 16) | s0;
      pk.y = ((unsigned)s3 << 16) | s2;
      reinterpret_cast<uint2*>(XaB)[o] = pk;
    } else if (b < 480) {
      const int o = (b - 224) * 256 + t;
      const int j = o >> 9, d = o & 511;
      W1aT[o] = bfc(W1a[d * DT + j]);
    } else if (b < 736) {
      const int o = (b - 480) * 256 + t;
      const int j = o >> 9, d = o & 511;
      W1vT[o] = bfc(W1v[d * DT + j]);
    } else if (b < 800) {
      const int o = (b - 736) * 256 + t;
      const int j = o >> 7, d = o & 127;
      W2aT[o] = bfc(W2a[d * DT + j]);
    } else {
      const int o = (b - 800) * 256 + t;
      const int j = o >> 7, d = o & 127;
      W2vT[o] = bfc(W2v[d * DT + j]);
    }
    return;
  }

  // ---------------- fg path (pipelined) ----------------
  const int lane = t & 63;
  const int w = t >> 6;
  const int col = lane & 15;
  const int kg = lane >> 4;
  const int n = blockIdx.x >> 1;
  const int half = blockIdx.x & 1;
  const int c0blk = half * 256;

  const float* featn = feat + ((size_t)n * D + c0blk) * HH;
  const float* camn = cam + (size_t)n * K * HH;

  const float* rowp0 = featn + (size_t)((w * 4 + 0) * 16 + col) * HH;
  const float* rowp1 = featn + (size_t)((w * 4 + 1) * 16 + col) * HH;
  const float* rowp2 = featn + (size_t)((w * 4 + 2) * 16 + col) * HH;
  const float* rowp3 = featn + (size_t)((w * 4 + 3) * 16 + col) * HH;

  // slab-0 preload FIRST (HBM starts streaming before the preamble)
  float4 alo[4], ahi[4];
  alo[0] = *reinterpret_cast<const float4*>(rowp0 + kg * 8);
  ahi[0] = *reinterpret_cast<const float4*>(rowp0 + kg * 8 + 4);
  alo[1] = *reinterpret_cast<const float4*>(rowp1 + kg * 8);
  ahi[1] = *reinterpret_cast<const float4*>(rowp1 + kg * 8 + 4);
  alo[2] = *reinterpret_cast<const float4*>(rowp2 + kg * 8);
  ahi[2] = *reinterpret_cast<const float4*>(rowp2 + kg * 8 + 4);
  alo[3] = *reinterpret_cast<const float4*>(rowp3 + kg * 8);
  ahi[3] = *reinterpret_cast<const float4*>(rowp3 + kg * 8 + 4);

  // ---- B fragments (cam, bf16) for 7 k-slabs ----
  bf16x8 bs[7];
  {
    const float* crow = camn + col * HH;
#pragma unroll
    for (int s = 0; s < 7; ++s) {
      float4 lo = make_float4(0.f, 0.f, 0.f, 0.f);
      float4 hi = make_float4(0.f, 0.f, 0.f, 0.f);
      if (col < 7) {
        if (s < 6) {
          lo = *reinterpret_cast<const float4*>(crow + s * 32 + kg * 8);
          hi = *reinterpret_cast<const float4*>(crow + s * 32 + kg * 8 + 4);
        } else if (kg == 0) {
          lo = *reinterpret_cast<const float4*>(crow + 192);
        }
      }
      bs[s] = cvt8(lo, hi);
    }
  }

  // ---- inv[col] via per-wave butterflies ----
  float invc = 0.f;
#pragma unroll
  for (int k = 0; k < K; ++k) {
    float4 cv = (lane < 49)
                    ? *reinterpret_cast<const float4*>(camn + k * HH + 4 * lane)
                    : make_float4(0.f, 0.f, 0.f, 0.f);
    float s = cv.x + cv.y + cv.z + cv.w;
#pragma unroll
    for (int m = 32; m >= 1; m >>= 1) s += __shfl_xor(s, m, 64);
    const float iv = 1.0f / (s + 1e-10f);
    if (col == k) invc = iv;
  }

  // ---- pipelined K loop: prefetch slab s+1, MFMA slab s (4 indep chains) ----
  f32x4 acc[4];
#pragma unroll
  for (int mt = 0; mt < 4; ++mt) acc[mt] = (f32x4){0.f, 0.f, 0.f, 0.f};

#pragma unroll
  for (int s = 0; s < 7; ++s) {
    float4 nlo[4], nhi[4];
    if (s < 5) {
      const int off = (s + 1) * 32 + kg * 8;
      nlo[0] = *reinterpret_cast<const float4*>(rowp0 + off);
      nhi[0] = *reinterpret_cast<const float4*>(rowp0 + off + 4);
      nlo[1] = *reinterpret_cast<const float4*>(rowp1 + off);
      nhi[1] = *reinterpret_cast<const float4*>(rowp1 + off + 4);
      nlo[2] = *reinterpret_cast<const float4*>(rowp2 + off);
      nhi[2] = *reinterpret_cast<const float4*>(rowp2 + off + 4);
      nlo[3] = *reinterpret_cast<const float4*>(rowp3 + off);
      nhi[3] = *reinterpret_cast<const float4*>(rowp3 + off + 4);
    } else if (s == 5) {  // next slab = tail (hw 192..195, kg==0 only)
      const float4 z = make_float4(0.f, 0.f, 0.f, 0.f);
      nlo[0] = (kg == 0) ? *reinterpret_cast<const float4*>(rowp0 + 192) : z;
      nlo[1] = (kg == 0) ? *reinterpret_cast<const float4*>(rowp1 + 192) : z;
      nlo[2] = (kg == 0) ? *reinterpret_cast<const float4*>(rowp2 + 192) : z;
      nlo[3] = (kg == 0) ? *reinterpret_cast<const float4*>(rowp3 + 192) : z;
      nhi[0] = z; nhi[1] = z; nhi[2] = z; nhi[3] = z;
    }

#pragma unroll
    for (int mt = 0; mt < 4; ++mt) {
      const bf16x8 a = cvt8(alo[mt], ahi[mt]);
      acc[mt] = __builtin_amdgcn_mfma_f32_16x16x32_bf16(a, bs[s], acc[mt], 0, 0, 0);
    }

    if (s < 6) {
#pragma unroll
      for (int mt = 0; mt < 4; ++mt) { alo[mt] = nlo[mt]; ahi[mt] = nhi[mt]; }
    }
  }

  // ---- writeback (bf16 packed) ----
  unsigned short* fgn = fgb + (size_t)n * K * D;
  if (col < 7) {
#pragma unroll
    for (int mt = 0; mt < 4; ++mt) {
      uint2 pk;
      pk.x = ((unsigned)bfc(acc[mt][1] * invc) << 16) | bfc(acc[mt][0] * invc);
      pk.y = ((unsigned)bfc(acc[mt][3] * invc) << 16) | bfc(acc[mt][2] * invc);
      *reinterpret_cast<uint2*>(
          fgn + (size_t)col * D + c0blk + (w * 4 + mt) * 16 + kg * 4) = pk;
    }
  }
}

// ---------------------------------------------------------------------------
// Kernel 2 (mlp3, MFMA, R14-validated): unchanged.
// ---------------------------------------------------------------------------
__global__ __launch_bounds__(256) void mlp3_kernel(
    const unsigned short* __restrict__ XaB, const unsigned short* __restrict__ XvB,
    const unsigned short* __restrict__ W1aT, const unsigned short* __restrict__ W2aT,
    const float* __restrict__ b1a, const float* __restrict__ b2a,
    const float* __restrict__ ga, const float* __restrict__ bna,
    const unsigned short* __restrict__ W1vT, const unsigned short* __restrict__ W2vT,
    const float* __restrict__ b1v, const float* __restrict__ b2v,
    const float* __restrict__ gv, const float* __restrict__ bnv,
    float* __restrict__ Ta, float* __restrict__ Tv) {
  __shared__ unsigned short hs[16 * 144];

  const int t = threadIdx.x;
  const int lane = t & 63;
  const int w = t >> 6;
  const int c15 = lane & 15;
  const int kg = lane >> 4;
  const int nbase = w * 32;
  const int b = blockIdx.x;

  const unsigned short *XB, *W1T, *W2T;
  const float *b1, *b2, *g, *bn;
  float* out;
  int r0;
  if (b < MLP_BLK_A) {
    XB = XaB; W1T = W1aT; W2T = W2aT; b1 = b1a; b2 = b2a; g = ga; bn = bna;
    out = Ta; r0 = b * 16;
  } else {
    XB = XvB; W1T = W1vT; W2T = W2vT; b1 = b1v; b2 = b2v; g = gv; bn = bnv;
    out = Tv; r0 = (b - MLP_BLK_A) * 16;
  }

  const unsigned short* xp = XB + (size_t)(r0 + c15) * D + kg * 8;
  const unsigned short* wp0 = W1T + (size_t)(nbase + c15) * D + kg * 8;
  const unsigned short* wp1 = W1T + (size_t)(nbase + 16 + c15) * D + kg * 8;

  f32x4 acc0 = {0.f, 0.f, 0.f, 0.f};
  f32x4 acc1 = {0.f, 0.f, 0.f, 0.f};
#pragma unroll
  for (int s = 0; s < 16; ++s) {
    const bf16x8 a = *reinterpret_cast<const bf16x8*>(xp + s * 32);
    const bf16x8 w0 = *reinterpret_cast<const bf16x8*>(wp0 + s * 32);
    const bf16x8 w1 = *reinterpret_cast<const bf16x8*>(wp1 + s * 32);
    acc0 = __builtin_amdgcn_mfma_f32_16x16x32_bf16(a, w0, acc0, 0, 0, 0);
    acc1 = __builtin_amdgcn_mfma_f32_16x16x32_bf16(a, w1, acc1, 0, 0, 0);
  }

  {
    const float bc0 = b1[nbase + c15];
    const float bc1 = b1[nbase + 16 + c15];
#pragma unroll
    for (int i = 0; i < 4; ++i) {
      const int row = kg * 4 + i;
      hs[row * 144 + nbase + c15] = bfc(fmaxf(acc0[i] + bc0, 0.f));
      hs[row * 144 + nbase + 16 + c15] = bfc(fmaxf(acc1[i] + bc1, 0.f));
    }
  }
  __syncthreads();

  const unsigned short* w2p0 = W2T + (size_t)(nbase + c15) * DT + kg * 8;
  const unsigned short* w2p1 = W2T + (size_t)(nbase + 16 + c15) * DT + kg * 8;
  f32x4 c0 = {0.f, 0.f, 0.f, 0.f};
  f32x4 c1 = {0.f, 0.f, 0.f, 0.f};
#pragma unroll
  for (int s = 0; s < 4; ++s) {
    const bf16x8 a = *reinterpret_cast<const bf16x8*>(hs + c15 * 144 + s * 32 + kg * 8);
    const bf16x8 w0 = *reinterpret_cast<const bf16x8*>(w2p0 + s * 32);
    const bf16x8 w1 = *reinterpret_cast<const bf16x8*>(w2p1 + s * 32);
    c0 = __builtin_amdgcn_mfma_f32_16x16x32_bf16(a, w0, c0, 0, 0, 0);
    c1 = __builtin_amdgcn_mfma_f32_16x16x32_bf16(a, w1, c1, 0, 0, 0);
  }

  {
    const int col0 = nbase + c15;
    const int col1 = nbase + 16 + c15;
    const float b20 = b2[col0], b21 = b2[col1];
    const float g0 = g[col0], g1 = g[col1];
    const float n0 = bn[col0], n1 = bn[col1];
#pragma unroll
    for (int i = 0; i < 4; ++i) {
      const int row = r0 + kg * 4 + i;
      out[(size_t)row * DT + col0] = (c0[i] + b20) * g0 + n0;
      out[(size_t)row * DT + col1] = (c1[i] + b21) * g1 + n1;
    }
  }
}

// ---------------------------------------------------------------------------
// Kernel 3: losses + masks (unchanged).
// ---------------------------------------------------------------------------
__global__ __launch_bounds__(256) void loss_kernel(
    const float* __restrict__ Ta, const float* __restrict__ Tv,
    const float* __restrict__ pred_a, const float* __restrict__ pred_v,
    const int* __restrict__ perm_idx, const int* __restrict__ cls_idx,
    float* __restrict__ out) {
  const int t = threadIdx.x;
  const int sub = t & 31;
  const int idx = blockIdx.x * 8 + (t >> 5);
  const int f = idx % F;
  const int k = (idx / F) % K;
  const int s = idx / (K * F);

  const int p = perm_idx[idx];
  const int c = cls_idx[idx];
  const int rowd = ((s ^ 1) * F + p) * K + c;

  float4 ta = reinterpret_cast<const float4*>(Ta)[(s * K + k) * 32 + sub];
  float4 tv = reinterpret_cast<const float4*>(Tv)[((s * F + f) * K + k) * 32 + sub];
  float4 td = reinterpret_cast<const float4*>(Tv)[rowd * 32 + sub];
  float d1 = 0.f, d2 = 0.f, e;
  e = ta.x - tv.x; d1 += e * e;
  e = ta.y - tv.y; d1 += e * e;
  e = ta.z - tv.z; d1 += e * e;
  e = ta.w - tv.w; d1 += e * e;
  e = ta.x - td.x; d2 += e * e;
  e = ta.y - td.y; d2 += e * e;
  e = ta.z - td.z; d2 += e * e;
  e = ta.w - td.w; d2 += e * e;
#pragma unroll
  for (int m = 16; m >= 1; m >>= 1) {
    d1 += __shfl_xor(d1, m, 64);
    d2 += __shfl_xor(d2, m, 64);
  }
  if (sub == 0) {
    float pa = pred_a[s * K + k];
    bool act = pa > 0.3f;
    int num = (int)floorf(pa * (float)F);
    float pvv = pred_v[(s * F + f) * K + k];
    float sg = 1.0f / (1.0f + expf(-pvv));
    bool mco = act && (sg > 0.3f);
    bool mdi = act && (f < num);
    float lco = d1 * (1.0f / 128.0f);
    float ldi = d2 * (1.0f / 128.0f);
    out[idx] = mco ? lco : 0.0f;
    out[NOUT + idx] = mdi ? ldi : 0.0f;
    out[2 * NOUT + idx] = mco ? 1.0f : 0.0f;
    out[3 * NOUT + idx] = mdi ? 1.0f : 0.0f;
  }
}

extern "C" void kernel_launch(void* const* d_in, const int* in_sizes, int n_in,
                              void* d_out, int out_size, void* d_ws, size_t ws_size,
                              hipStream_t stream) {
  const float* feat_a     = (const float*)d_in[0];
  const float* pred_a     = (const float*)d_in[1];
  const float* feat_v_raw = (const float*)d_in[2];
  const float* pred_v     = (const float*)d_in[3];
  const float* cam        = (const float*)d_in[4];
  const float* W1a = (const float*)d_in[5];
  const float* b1a = (const float*)d_in[6];
  const float* W2a = (const float*)d_in[7];
  const float* b2a = (const float*)d_in[8];
  const float* ga  = (const float*)d_in[9];
  const float* bna = (const float*)d_in[10];
  const float* W1v = (const float*)d_in[11];
  const float* b1v = (const float*)d_in[12];
  const float* W2v = (const float*)d_in[13];
  const float* b2v = (const float*)d_in[14];
  const float* gv  = (const float*)d_in[15];
  const float* bnv = (const float*)d_in[16];
  const int* perm_idx = (const int*)d_in[17];
  const int* cls_idx  = (const int*)d_in[18];
  float* out = (float*)d_out;

  char* w = (char*)d_ws;
  unsigned short* fgb  = (unsigned short*)(w);
  unsigned short* XaB  = (unsigned short*)(w + 4587520);
  unsigned short* W1aT = (unsigned short*)(w + 4587520 + 458752);
  unsigned short* W1vT = (unsigned short*)(w + 4587520 + 458752 + 131072);
  unsigned short* W2aT = (unsigned short*)(w + 4587520 + 458752 + 262144);
  unsigned short* W2vT = (unsigned short*)(w + 4587520 + 458752 + 262144 + 32768);
  float* Ta = (float*)(w + 4587520 + 458752 + 262144 + 65536);
  float* Tv = (float*)(w + 4587520 + 458752 + 262144 + 65536 + 229376);

  fgconv_kernel<<<FG_BLKS + CONV_BLKS, 256, 0, stream>>>(
      feat_v_raw, cam, fgb, feat_a, W1a, W1v, W2a, W2v,
      XaB, W1aT, W1vT, W2aT, W2vT);
  mlp3_kernel<<<MLP_BLK_A + MLP_BLK_V, 256, 0, stream>>>(
      XaB, fgb, W1aT, W2aT, b1a, b2a, ga, bna,
      W1vT, W2vT, b1v, b2v, gv, bnv, Ta, Tv);
  loss_kernel<<<NOUT / 8, 256, 0, stream>>>(Ta, Tv, pred_a, pred_v, perm_idx,
                                            cls_idx, out);
}

// Round 18
// 83.949 us; speedup vs baseline: 2.2028x; 1.0575x over previous
//
#include <hip/hip_runtime.h>
#include <hip/hip_bf16.h>
#include <math.h>

// Problem constants
#define S 64
#define F 10
#define K 7
#define D 512
#define HH 196   // H*H = 14*14
#define DT 128
#define NF (S*F)          // 640
#define NROWS_V (S*F*K)   // 4480
#define NROWS_A (S*K)     // 448
#define NOUT (S*K*F)      // 4480
#define MLP_BLK_A (NROWS_A / 16)   // 28
#define MLP_BLK_V (NROWS_V / 16)   // 280
#define FG_BLKS (NF * 2)           // 1280
#define CONV_BLKS 864

typedef short bf16x8 __attribute__((ext_vector_type(8)));
typedef float f32x4 __attribute__((ext_vector_type(4)));

__device__ __forceinline__ unsigned short bfc(float x) {
  __hip_bfloat16 h = __float2bfloat16(x);
  return *reinterpret_cast<unsigned short*>(&h);
}

__device__ __forceinline__ bf16x8 cvt8(const float4& lo, const float4& hi) {
  bf16x8 a;
  a[0] = (short)bfc(lo.x); a[1] = (short)bfc(lo.y);
  a[2] = (short)bfc(lo.z); a[3] = (short)bfc(lo.w);
  a[4] = (short)bfc(hi.x); a[5] = (short)bfc(hi.y);
  a[6] = (short)bfc(hi.z); a[7] = (short)bfc(hi.w);
  return a;
}

// ---------------------------------------------------------------------------
// Kernel 1 (v13): fused fg-MFMA + conversions, software-pipelined fg.
// Identical to R17's v12 EXCEPT no min-waves launch bound: v12's
// __launch_bounds__(256,4) capped VGPR at 128 < the ~140 the 2-slab-deep
// prefetch needs -> scratch spills (+21us). Unbounded, VGPR ~120-150 ->
// no spills; occupancy ~12 waves/CU = R16's measured value -> pure win
// from continuous load stream + 4 independent MFMA chains.
// ---------------------------------------------------------------------------
__global__ __launch_bounds__(256) void fgconv_kernel(
    const float* __restrict__ feat, const float* __restrict__ cam,
    unsigned short* __restrict__ fgb,
    const float* __restrict__ feat_a,
    const float* __restrict__ W1a, const float* __restrict__ W1v,
    const float* __restrict__ W2a, const float* __restrict__ W2v,
    unsigned short* __restrict__ XaB,
    unsigned short* __restrict__ W1aT, unsigned short* __restrict__ W1vT,
    unsigned short* __restrict__ W2aT, unsigned short* __restrict__ W2vT) {
  const int t = threadIdx.x;

  if (blockIdx.x >= FG_BLKS) {
    // ---------------- conv path ----------------
    const int b = blockIdx.x - FG_BLKS;
    if (b < 224) {  // feat_a: 57344 float4
      const int o = b * 256 + t;
      const float4 v = reinterpret_cast<const float4*>(feat_a)[o];
      unsigned short s0 = bfc(v.x), s1 = bfc(v.y), s2 = bfc(v.z), s3 = bfc(v.w);
      uint2 pk;
      pk.x = ((unsigned)s1 << 16) | s0;
      pk.y = ((unsigned)s3 << 16) | s2;
      reinterpret_cast<uint2*>(XaB)[o] = pk;
    } else if (b < 480) {
      const int o = (b - 224) * 256 + t;
      const int j = o >> 9, d = o & 511;
      W1aT[o] = bfc(W1a[d * DT + j]);
    } else if (b < 736) {
      const int o = (b - 480) * 256 + t;
      const int j = o >> 9, d = o & 511;
      W1vT[o] = bfc(W1v[d * DT + j]);
    } else if (b < 800) {
      const int o = (b - 736) * 256 + t;
      const int j = o >> 7, d = o & 127;
      W2aT[o] = bfc(W2a[d * DT + j]);
    } else {
      const int o = (b - 800) * 256 + t;
      const int j = o >> 7, d = o & 127;
      W2vT[o] = bfc(W2v[d * DT + j]);
    }
    return;
  }

  // ---------------- fg path (pipelined) ----------------
  const int lane = t & 63;
  const int w = t >> 6;
  const int col = lane & 15;
  const int kg = lane >> 4;
  const int n = blockIdx.x >> 1;
  const int half = blockIdx.x & 1;
  const int c0blk = half * 256;

  const float* featn = feat + ((size_t)n * D + c0blk) * HH;
  const float* camn = cam + (size_t)n * K * HH;

  const float* rowp0 = featn + (size_t)((w * 4 + 0) * 16 + col) * HH;
  const float* rowp1 = featn + (size_t)((w * 4 + 1) * 16 + col) * HH;
  const float* rowp2 = featn + (size_t)((w * 4 + 2) * 16 + col) * HH;
  const float* rowp3 = featn + (size_t)((w * 4 + 3) * 16 + col) * HH;

  // slab-0 preload FIRST (HBM starts streaming before the preamble)
  float4 alo[4], ahi[4];
  alo[0] = *reinterpret_cast<const float4*>(rowp0 + kg * 8);
  ahi[0] = *reinterpret_cast<const float4*>(rowp0 + kg * 8 + 4);
  alo[1] = *reinterpret_cast<const float4*>(rowp1 + kg * 8);
  ahi[1] = *reinterpret_cast<const float4*>(rowp1 + kg * 8 + 4);
  alo[2] = *reinterpret_cast<const float4*>(rowp2 + kg * 8);
  ahi[2] = *reinterpret_cast<const float4*>(rowp2 + kg * 8 + 4);
  alo[3] = *reinterpret_cast<const float4*>(rowp3 + kg * 8);
  ahi[3] = *reinterpret_cast<const float4*>(rowp3 + kg * 8 + 4);

  // ---- B fragments (cam, bf16) for 7 k-slabs ----
  bf16x8 bs[7];
  {
    const float* crow = camn + col * HH;
#pragma unroll
    for (int s = 0; s < 7; ++s) {
      float4 lo = make_float4(0.f, 0.f, 0.f, 0.f);
      float4 hi = make_float4(0.f, 0.f, 0.f, 0.f);
      if (col < 7) {
        if (s < 6) {
          lo = *reinterpret_cast<const float4*>(crow + s * 32 + kg * 8);
          hi = *reinterpret_cast<const float4*>(crow + s * 32 + kg * 8 + 4);
        } else if (kg == 0) {
          lo = *reinterpret_cast<const float4*>(crow + 192);
        }
      }
      bs[s] = cvt8(lo, hi);
    }
  }

  // ---- inv[col] via per-wave butterflies ----
  float invc = 0.f;
#pragma unroll
  for (int k = 0; k < K; ++k) {
    float4 cv = (lane < 49)
                    ? *reinterpret_cast<const float4*>(camn + k * HH + 4 * lane)
                    : make_float4(0.f, 0.f, 0.f, 0.f);
    float s = cv.x + cv.y + cv.z + cv.w;
#pragma unroll
    for (int m = 32; m >= 1; m >>= 1) s += __shfl_xor(s, m, 64);
    const float iv = 1.0f / (s + 1e-10f);
    if (col == k) invc = iv;
  }

  // ---- pipelined K loop: prefetch slab s+1, MFMA slab s (4 indep chains) ----
  f32x4 acc[4];
#pragma unroll
  for (int mt = 0; mt < 4; ++mt) acc[mt] = (f32x4){0.f, 0.f, 0.f, 0.f};

#pragma unroll
  for (int s = 0; s < 7; ++s) {
    float4 nlo[4], nhi[4];
    if (s < 5) {
      const int off = (s + 1) * 32 + kg * 8;
      nlo[0] = *reinterpret_cast<const float4*>(rowp0 + off);
      nhi[0] = *reinterpret_cast<const float4*>(rowp0 + off + 4);
      nlo[1] = *reinterpret_cast<const float4*>(rowp1 + off);
      nhi[1] = *reinterpret_cast<const float4*>(rowp1 + off + 4);
      nlo[2] = *reinterpret_cast<const float4*>(rowp2 + off);
      nhi[2] = *reinterpret_cast<const float4*>(rowp2 + off + 4);
      nlo[3] = *reinterpret_cast<const float4*>(rowp3 + off);
      nhi[3] = *reinterpret_cast<const float4*>(rowp3 + off + 4);
    } else if (s == 5) {  // next slab = tail (hw 192..195, kg==0 only)
      const float4 z = make_float4(0.f, 0.f, 0.f, 0.f);
      nlo[0] = (kg == 0) ? *reinterpret_cast<const float4*>(rowp0 + 192) : z;
      nlo[1] = (kg == 0) ? *reinterpret_cast<const float4*>(rowp1 + 192) : z;
      nlo[2] = (kg == 0) ? *reinterpret_cast<const float4*>(rowp2 + 192) : z;
      nlo[3] = (kg == 0) ? *reinterpret_cast<const float4*>(rowp3 + 192) : z;
      nhi[0] = z; nhi[1] = z; nhi[2] = z; nhi[3] = z;
    }

#pragma unroll
    for (int mt = 0; mt < 4; ++mt) {
      const bf16x8 a = cvt8(alo[mt], ahi[mt]);
      acc[mt] = __builtin_amdgcn_mfma_f32_16x16x32_bf16(a, bs[s], acc[mt], 0, 0, 0);
    }

    if (s < 6) {
#pragma unroll
      for (int mt = 0; mt < 4; ++mt) { alo[mt] = nlo[mt]; ahi[mt] = nhi[mt]; }
    }
  }

  // ---- writeback (bf16 packed) ----
  unsigned short* fgn = fgb + (size_t)n * K * D;
  if (col < 7) {
#pragma unroll
    for (int mt = 0; mt < 4; ++mt) {
      uint2 pk;
      pk.x = ((unsigned)bfc(acc[mt][1] * invc) << 16) | bfc(acc[mt][0] * invc);
      pk.y = ((unsigned)bfc(acc[mt][3] * invc) << 16) | bfc(acc[mt][2] * invc);
      *reinterpret_cast<uint2*>(
          fgn + (size_t)col * D + c0blk + (w * 4 + mt) * 16 + kg * 4) = pk;
    }
  }
}

// ---------------------------------------------------------------------------
// Kernel 2 (mlp3, MFMA, R14-validated): unchanged.
// ---------------------------------------------------------------------------
__global__ __launch_bounds__(256) void mlp3_kernel(
    const unsigned short* __restrict__ XaB, const unsigned short* __restrict__ XvB,
    const unsigned short* __restrict__ W1aT, const unsigned short* __restrict__ W2aT,
    const float* __restrict__ b1a, const float* __restrict__ b2a,
    const float* __restrict__ ga, const float* __restrict__ bna,
    const unsigned short* __restrict__ W1vT, const unsigned short* __restrict__ W2vT,
    const float* __restrict__ b1v, const float* __restrict__ b2v,
    const float* __restrict__ gv, const float* __restrict__ bnv,
    float* __restrict__ Ta, float* __restrict__ Tv) {
  __shared__ unsigned short hs[16 * 144];

  const int t = threadIdx.x;
  const int lane = t & 63;
  const int w = t >> 6;
  const int c15 = lane & 15;
  const int kg = lane >> 4;
  const int nbase = w * 32;
  const int b = blockIdx.x;

  const unsigned short *XB, *W1T, *W2T;
  const float *b1, *b2, *g, *bn;
  float* out;
  int r0;
  if (b < MLP_BLK_A) {
    XB = XaB; W1T = W1aT; W2T = W2aT; b1 = b1a; b2 = b2a; g = ga; bn = bna;
    out = Ta; r0 = b * 16;
  } else {
    XB = XvB; W1T = W1vT; W2T = W2vT; b1 = b1v; b2 = b2v; g = gv; bn = bnv;
    out = Tv; r0 = (b - MLP_BLK_A) * 16;
  }

  const unsigned short* xp = XB + (size_t)(r0 + c15) * D + kg * 8;
  const unsigned short* wp0 = W1T + (size_t)(nbase + c15) * D + kg * 8;
  const unsigned short* wp1 = W1T + (size_t)(nbase + 16 + c15) * D + kg * 8;

  f32x4 acc0 = {0.f, 0.f, 0.f, 0.f};
  f32x4 acc1 = {0.f, 0.f, 0.f, 0.f};
#pragma unroll
  for (int s = 0; s < 16; ++s) {
    const bf16x8 a = *reinterpret_cast<const bf16x8*>(xp + s * 32);
    const bf16x8 w0 = *reinterpret_cast<const bf16x8*>(wp0 + s * 32);
    const bf16x8 w1 = *reinterpret_cast<const bf16x8*>(wp1 + s * 32);
    acc0 = __builtin_amdgcn_mfma_f32_16x16x32_bf16(a, w0, acc0, 0, 0, 0);
    acc1 = __builtin_amdgcn_mfma_f32_16x16x32_bf16(a, w1, acc1, 0, 0, 0);
  }

  {
    const float bc0 = b1[nbase + c15];
    const float bc1 = b1[nbase + 16 + c15];
#pragma unroll
    for (int i = 0; i < 4; ++i) {
      const int row = kg * 4 + i;
      hs[row * 144 + nbase + c15] = bfc(fmaxf(acc0[i] + bc0, 0.f));
      hs[row * 144 + nbase + 16 + c15] = bfc(fmaxf(acc1[i] + bc1, 0.f));
    }
  }
  __syncthreads();

  const unsigned short* w2p0 = W2T + (size_t)(nbase + c15) * DT + kg * 8;
  const unsigned short* w2p1 = W2T + (size_t)(nbase + 16 + c15) * DT + kg * 8;
  f32x4 c0 = {0.f, 0.f, 0.f, 0.f};
  f32x4 c1 = {0.f, 0.f, 0.f, 0.f};
#pragma unroll
  for (int s = 0; s < 4; ++s) {
    const bf16x8 a = *reinterpret_cast<const bf16x8*>(hs + c15 * 144 + s * 32 + kg * 8);
    const bf16x8 w0 = *reinterpret_cast<const bf16x8*>(w2p0 + s * 32);
    const bf16x8 w1 = *reinterpret_cast<const bf16x8*>(w2p1 + s * 32);
    c0 = __builtin_amdgcn_mfma_f32_16x16x32_bf16(a, w0, c0, 0, 0, 0);
    c1 = __builtin_amdgcn_mfma_f32_16x16x32_bf16(a, w1, c1, 0, 0, 0);
  }

  {
    const int col0 = nbase + c15;
    const int col1 = nbase + 16 + c15;
    const float b20 = b2[col0], b21 = b2[col1];
    const float g0 = g[col0], g1 = g[col1];
    const float n0 = bn[col0], n1 = bn[col1];
#pragma unroll
    for (int i = 0; i < 4; ++i) {
      const int row = r0 + kg * 4 + i;
      out[(size_t)row * DT + col0] = (c0[i] + b20) * g0 + n0;
      out[(size_t)row * DT + col1] = (c1[i] + b21) * g1 + n1;
    }
  }
}

// ---------------------------------------------------------------------------
// Kernel 3: losses + masks (unchanged).
// ---------------------------------------------------------------------------
__global__ __launch_bounds__(256) void loss_kernel(
    const float* __restrict__ Ta, const float* __restrict__ Tv,
    const float* __restrict__ pred_a, const float* __restrict__ pred_v,
    const int* __restrict__ perm_idx, const int* __restrict__ cls_idx,
    float* __restrict__ out) {
  const int t = threadIdx.x;
  const int sub = t & 31;
  const int idx = blockIdx.x * 8 + (t >> 5);
  const int f = idx % F;
  const int k = (idx / F) % K;
  const int s = idx / (K * F);

  const int p = perm_idx[idx];
  const int c = cls_idx[idx];
  const int rowd = ((s ^ 1) * F + p) * K + c;

  float4 ta = reinterpret_cast<const float4*>(Ta)[(s * K + k) * 32 + sub];
  float4 tv = reinterpret_cast<const float4*>(Tv)[((s * F + f) * K + k) * 32 + sub];
  float4 td = reinterpret_cast<const float4*>(Tv)[rowd * 32 + sub];
  float d1 = 0.f, d2 = 0.f, e;
  e = ta.x - tv.x; d1 += e * e;
  e = ta.y - tv.y; d1 += e * e;
  e = ta.z - tv.z; d1 += e * e;
  e = ta.w - tv.w; d1 += e * e;
  e = ta.x - td.x; d2 += e * e;
  e = ta.y - td.y; d2 += e * e;
  e = ta.z - td.z; d2 += e * e;
  e = ta.w - td.w; d2 += e * e;
#pragma unroll
  for (int m = 16; m >= 1; m >>= 1) {
    d1 += __shfl_xor(d1, m, 64);
    d2 += __shfl_xor(d2, m, 64);
  }
  if (sub == 0) {
    float pa = pred_a[s * K + k];
    bool act = pa > 0.3f;
    int num = (int)floorf(pa * (float)F);
    float pvv = pred_v[(s * F + f) * K + k];
    float sg = 1.0f / (1.0f + expf(-pvv));
    bool mco = act && (sg > 0.3f);
    bool mdi = act && (f < num);
    float lco = d1 * (1.0f / 128.0f);
    float ldi = d2 * (1.0f / 128.0f);
    out[idx] = mco ? lco : 0.0f;
    out[NOUT + idx] = mdi ? ldi : 0.0f;
    out[2 * NOUT + idx] = mco ? 1.0f : 0.0f;
    out[3 * NOUT + idx] = mdi ? 1.0f : 0.0f;
  }
}

extern "C" void kernel_launch(void* const* d_in, const int* in_sizes, int n_in,
                              void* d_out, int out_size, void* d_ws, size_t ws_size,
                              hipStream_t stream) {
  const float* feat_a     = (const float*)d_in[0];
  const float* pred_a     = (const float*)d_in[1];
  const float* feat_v_raw = (const float*)d_in[2];
  const float* pred_v     = (const float*)d_in[3];
  const float* cam        = (const float*)d_in[4];
  const float* W1a = (const float*)d_in[5];
  const float* b1a = (const float*)d_in[6];
  const float* W2a = (const float*)d_in[7];
  const float* b2a = (const float*)d_in[8];
  const float* ga  = (const float*)d_in[9];
  const float* bna = (const float*)d_in[10];
  const float* W1v = (const float*)d_in[11];
  const float* b1v = (const float*)d_in[12];
  const float* W2v = (const float*)d_in[13];
  const float* b2v = (const float*)d_in[14];
  const float* gv  = (const float*)d_in[15];
  const float* bnv = (const float*)d_in[16];
  const int* perm_idx = (const int*)d_in[17];
  const int* cls_idx  = (const int*)d_in[18];
  float* out = (float*)d_out;

  char* w = (char*)d_ws;
  unsigned short* fgb  = (unsigned short*)(w);
  unsigned short* XaB  = (unsigned short*)(w + 4587520);
  unsigned short* W1aT = (unsigned short*)(w + 4587520 + 458752);
  unsigned short* W1vT = (unsigned short*)(w + 4587520 + 458752 + 131072);
  unsigned short* W2aT = (unsigned short*)(w + 4587520 + 458752 + 262144);
  unsigned short* W2vT = (unsigned short*)(w + 4587520 + 458752 + 262144 + 32768);
  float* Ta = (float*)(w + 4587520 + 458752 + 262144 + 65536);
  float* Tv = (float*)(w + 4587520 + 458752 + 262144 + 65536 + 229376);

  fgconv_kernel<<<FG_BLKS + CONV_BLKS, 256, 0, stream>>>(
      feat_v_raw, cam, fgb, feat_a, W1a, W1v, W2a, W2v,
      XaB, W1aT, W1vT, W2aT, W2vT);
  mlp3_kernel<<<MLP_BLK_A + MLP_BLK_V, 256, 0, stream>>>(
      XaB, fgb, W1aT, W2aT, b1a, b2a, ga, bna,
      W1vT, W2vT, b1v, b2v, gv, bnv, Ta, Tv);
  loss_kernel<<<NOUT / 8, 256, 0, stream>>>(Ta, Tv, pred_a, pred_v, perm_idx,
                                            cls_idx, out);
}

// Round 19
// 67.575 us; speedup vs baseline: 2.7366x; 1.2423x over previous
//
#include <hip/hip_runtime.h>
#include <hip/hip_bf16.h>
#include <math.h>

// Problem constants
#define S 64
#define F 10
#define K 7
#define D 512
#define HH 196   // H*H = 14*14
#define DT 128
#define NF (S*F)          // 640
#define NROWS_V (S*F*K)   // 4480
#define NROWS_A (S*K)     // 448
#define NOUT (S*K*F)      // 4480
#define MLP_BLK_A (NROWS_A / 16)   // 28
#define MLP_BLK_V (NROWS_V / 16)   // 280
#define FG_BLKS (NF * 2)           // 1280
#define CONV_BLKS 864

typedef short bf16x8 __attribute__((ext_vector_type(8)));
typedef float f32x4 __attribute__((ext_vector_type(4)));

__device__ __forceinline__ unsigned short bfc(float x) {
  __hip_bfloat16 h = __float2bfloat16(x);
  return *reinterpret_cast<unsigned short*>(&h);
}

// ---------------------------------------------------------------------------
// Kernel 1 (v11, R15-measured 67.1us total — best config, reverted to after
// the pipelined v12/v13 regressed): fused fg-MFMA + input conversions.
// Blocks [0,1280): fg = per-n C[512x7] = feat[512x196] x cam^T[196x7] via
//   mfma_f32_16x16x32_bf16 (conventions HW-validated R11/R13, absmax 6e-5);
//   output written as bf16 (mlp3 A operand).
// Blocks [1280,2144): conv = feat_a f32->bf16 and W1/W2 -> transposed bf16;
//   backfills CUs while fg streams.
// R16 direct counters for this fg: 55us/rep, VALUBusy 8.9%, MfmaUtil 1.7%,
// conflicts 0, runtime identical L3-warm vs HBM-cold => request-path-bound
// gather; LDS staging, DS-light, and SW-pipeline variants all slower.
// ---------------------------------------------------------------------------
__global__ __launch_bounds__(256) void fgconv_kernel(
    const float* __restrict__ feat, const float* __restrict__ cam,
    unsigned short* __restrict__ fgb,
    const float* __restrict__ feat_a,
    const float* __restrict__ W1a, const float* __restrict__ W1v,
    const float* __restrict__ W2a, const float* __restrict__ W2v,
    unsigned short* __restrict__ XaB,
    unsigned short* __restrict__ W1aT, unsigned short* __restrict__ W1vT,
    unsigned short* __restrict__ W2aT, unsigned short* __restrict__ W2vT) {
  const int t = threadIdx.x;

  if (blockIdx.x >= FG_BLKS) {
    // ---------------- conv path ----------------
    const int b = blockIdx.x - FG_BLKS;
    if (b < 224) {  // feat_a: 57344 float4
      const int o = b * 256 + t;
      const float4 v = reinterpret_cast<const float4*>(feat_a)[o];
      unsigned short s0 = bfc(v.x), s1 = bfc(v.y), s2 = bfc(v.z), s3 = bfc(v.w);
      uint2 pk;
      pk.x = ((unsigned)s1 << 16) | s0;
      pk.y = ((unsigned)s3 << 16) | s2;
      reinterpret_cast<uint2*>(XaB)[o] = pk;
    } else if (b < 480) {
      const int o = (b - 224) * 256 + t;
      const int j = o >> 9, d = o & 511;
      W1aT[o] = bfc(W1a[d * DT + j]);
    } else if (b < 736) {
      const int o = (b - 480) * 256 + t;
      const int j = o >> 9, d = o & 511;
      W1vT[o] = bfc(W1v[d * DT + j]);
    } else if (b < 800) {
      const int o = (b - 736) * 256 + t;
      const int j = o >> 7, d = o & 127;
      W2aT[o] = bfc(W2a[d * DT + j]);
    } else {
      const int o = (b - 800) * 256 + t;
      const int j = o >> 7, d = o & 127;
      W2vT[o] = bfc(W2v[d * DT + j]);
    }
    return;
  }

  // ---------------- fg path ----------------
  const int lane = t & 63;
  const int w = t >> 6;
  const int col = lane & 15;
  const int kg = lane >> 4;
  const int n = blockIdx.x >> 1;
  const int half = blockIdx.x & 1;
  const int c0blk = half * 256;

  const float* featn = feat + ((size_t)n * D + c0blk) * HH;
  const float* camn = cam + (size_t)n * K * HH;

  bf16x8 bs[7];
  {
    const float* crow = camn + col * HH;
#pragma unroll
    for (int s = 0; s < 7; ++s) {
      float v0 = 0.f, v1 = 0.f, v2 = 0.f, v3 = 0.f;
      float v4 = 0.f, v5 = 0.f, v6 = 0.f, v7 = 0.f;
      if (col < 7) {
        if (s < 6) {
          const float4 lo = *reinterpret_cast<const float4*>(crow + s * 32 + kg * 8);
          const float4 hi = *reinterpret_cast<const float4*>(crow + s * 32 + kg * 8 + 4);
          v0 = lo.x; v1 = lo.y; v2 = lo.z; v3 = lo.w;
          v4 = hi.x; v5 = hi.y; v6 = hi.z; v7 = hi.w;
        } else if (kg == 0) {
          const float4 lo = *reinterpret_cast<const float4*>(crow + 192);
          v0 = lo.x; v1 = lo.y; v2 = lo.z; v3 = lo.w;
        }
      }
      bs[s][0] = bfc(v0); bs[s][1] = bfc(v1); bs[s][2] = bfc(v2); bs[s][3] = bfc(v3);
      bs[s][4] = bfc(v4); bs[s][5] = bfc(v5); bs[s][6] = bfc(v6); bs[s][7] = bfc(v7);
    }
  }

  float invc = 0.f;
#pragma unroll
  for (int k = 0; k < K; ++k) {
    float4 cv = (lane < 49)
                    ? *reinterpret_cast<const float4*>(camn + k * HH + 4 * lane)
                    : make_float4(0.f, 0.f, 0.f, 0.f);
    float s = cv.x + cv.y + cv.z + cv.w;
#pragma unroll
    for (int m = 32; m >= 1; m >>= 1) s += __shfl_xor(s, m, 64);
    const float iv = 1.0f / (s + 1e-10f);
    if (col == k) invc = iv;
  }

  unsigned short* fgn = fgb + (size_t)n * K * D;

#pragma unroll
  for (int mt = 0; mt < 4; ++mt) {
    const int chl = (w * 4 + mt) * 16 + col;
    const float* rowp = featn + (size_t)chl * HH;

    f32x4 acc = {0.f, 0.f, 0.f, 0.f};
#pragma unroll
    for (int s = 0; s < 7; ++s) {
      float v0 = 0.f, v1 = 0.f, v2 = 0.f, v3 = 0.f;
      float v4 = 0.f, v5 = 0.f, v6 = 0.f, v7 = 0.f;
      if (s < 6) {
        const float4 lo = *reinterpret_cast<const float4*>(rowp + s * 32 + kg * 8);
        const float4 hi = *reinterpret_cast<const float4*>(rowp + s * 32 + kg * 8 + 4);
        v0 = lo.x; v1 = lo.y; v2 = lo.z; v3 = lo.w;
        v4 = hi.x; v5 = hi.y; v6 = hi.z; v7 = hi.w;
      } else if (kg == 0) {
        const float4 lo = *reinterpret_cast<const float4*>(rowp + 192);
        v0 = lo.x; v1 = lo.y; v2 = lo.z; v3 = lo.w;
      }
      bf16x8 a;
      a[0] = bfc(v0); a[1] = bfc(v1); a[2] = bfc(v2); a[3] = bfc(v3);
      a[4] = bfc(v4); a[5] = bfc(v5); a[6] = bfc(v6); a[7] = bfc(v7);
      acc = __builtin_amdgcn_mfma_f32_16x16x32_bf16(a, bs[s], acc, 0, 0, 0);
    }

    if (col < 7) {
      uint2 pk;
      pk.x = ((unsigned)bfc(acc[1] * invc) << 16) | bfc(acc[0] * invc);
      pk.y = ((unsigned)bfc(acc[3] * invc) << 16) | bfc(acc[2] * invc);
      *reinterpret_cast<uint2*>(
          fgn + (size_t)col * D + c0blk + (w * 4 + mt) * 16 + kg * 4) = pk;
    }
  }
}

// ---------------------------------------------------------------------------
// Kernel 2 (mlp3, MFMA, R14-validated): 16 rows x 128 cols per block, layer1
// 16 k-slabs from global bf16 X / W1T, h through padded LDS (one barrier),
// layer2 4 k-slabs vs W2T, fused bias+relu+affine epilogue.
// ---------------------------------------------------------------------------
__global__ __launch_bounds__(256) void mlp3_kernel(
    const unsigned short* __restrict__ XaB, const unsigned short* __restrict__ XvB,
    const unsigned short* __restrict__ W1aT, const unsigned short* __restrict__ W2aT,
    const float* __restrict__ b1a, const float* __restrict__ b2a,
    const float* __restrict__ ga, const float* __restrict__ bna,
    const unsigned short* __restrict__ W1vT, const unsigned short* __restrict__ W2vT,
    const float* __restrict__ b1v, const float* __restrict__ b2v,
    const float* __restrict__ gv, const float* __restrict__ bnv,
    float* __restrict__ Ta, float* __restrict__ Tv) {
  __shared__ unsigned short hs[16 * 144];

  const int t = threadIdx.x;
  const int lane = t & 63;
  const int w = t >> 6;
  const int c15 = lane & 15;
  const int kg = lane >> 4;
  const int nbase = w * 32;
  const int b = blockIdx.x;

  const unsigned short *XB, *W1T, *W2T;
  const float *b1, *b2, *g, *bn;
  float* out;
  int r0;
  if (b < MLP_BLK_A) {
    XB = XaB; W1T = W1aT; W2T = W2aT; b1 = b1a; b2 = b2a; g = ga; bn = bna;
    out = Ta; r0 = b * 16;
  } else {
    XB = XvB; W1T = W1vT; W2T = W2vT; b1 = b1v; b2 = b2v; g = gv; bn = bnv;
    out = Tv; r0 = (b - MLP_BLK_A) * 16;
  }

  const unsigned short* xp = XB + (size_t)(r0 + c15) * D + kg * 8;
  const unsigned short* wp0 = W1T + (size_t)(nbase + c15) * D + kg * 8;
  const unsigned short* wp1 = W1T + (size_t)(nbase + 16 + c15) * D + kg * 8;

  f32x4 acc0 = {0.f, 0.f, 0.f, 0.f};
  f32x4 acc1 = {0.f, 0.f, 0.f, 0.f};
#pragma unroll
  for (int s = 0; s < 16; ++s) {
    const bf16x8 a = *reinterpret_cast<const bf16x8*>(xp + s * 32);
    const bf16x8 w0 = *reinterpret_cast<const bf16x8*>(wp0 + s * 32);
    const bf16x8 w1 = *reinterpret_cast<const bf16x8*>(wp1 + s * 32);
    acc0 = __builtin_amdgcn_mfma_f32_16x16x32_bf16(a, w0, acc0, 0, 0, 0);
    acc1 = __builtin_amdgcn_mfma_f32_16x16x32_bf16(a, w1, acc1, 0, 0, 0);
  }

  {
    const float bc0 = b1[nbase + c15];
    const float bc1 = b1[nbase + 16 + c15];
#pragma unroll
    for (int i = 0; i < 4; ++i) {
      const int row = kg * 4 + i;
      hs[row * 144 + nbase + c15] = bfc(fmaxf(acc0[i] + bc0, 0.f));
      hs[row * 144 + nbase + 16 + c15] = bfc(fmaxf(acc1[i] + bc1, 0.f));
    }
  }
  __syncthreads();

  const unsigned short* w2p0 = W2T + (size_t)(nbase + c15) * DT + kg * 8;
  const unsigned short* w2p1 = W2T + (size_t)(nbase + 16 + c15) * DT + kg * 8;
  f32x4 c0 = {0.f, 0.f, 0.f, 0.f};
  f32x4 c1 = {0.f, 0.f, 0.f, 0.f};
#pragma unroll
  for (int s = 0; s < 4; ++s) {
    const bf16x8 a = *reinterpret_cast<const bf16x8*>(hs + c15 * 144 + s * 32 + kg * 8);
    const bf16x8 w0 = *reinterpret_cast<const bf16x8*>(w2p0 + s * 32);
    const bf16x8 w1 = *reinterpret_cast<const bf16x8*>(w2p1 + s * 32);
    c0 = __builtin_amdgcn_mfma_f32_16x16x32_bf16(a, w0, c0, 0, 0, 0);
    c1 = __builtin_amdgcn_mfma_f32_16x16x32_bf16(a, w1, c1, 0, 0, 0);
  }

  {
    const int col0 = nbase + c15;
    const int col1 = nbase + 16 + c15;
    const float b20 = b2[col0], b21 = b2[col1];
    const float g0 = g[col0], g1 = g[col1];
    const float n0 = bn[col0], n1 = bn[col1];
#pragma unroll
    for (int i = 0; i < 4; ++i) {
      const int row = r0 + kg * 4 + i;
      out[(size_t)row * DT + col0] = (c0[i] + b20) * g0 + n0;
      out[(size_t)row * DT + col1] = (c1[i] + b21) * g1 + n1;
    }
  }
}

// ---------------------------------------------------------------------------
// Kernel 3: losses + masks (unchanged).
// ---------------------------------------------------------------------------
__global__ __launch_bounds__(256) void loss_kernel(
    const float* __restrict__ Ta, const float* __restrict__ Tv,
    const float* __restrict__ pred_a, const float* __restrict__ pred_v,
    const int* __restrict__ perm_idx, const int* __restrict__ cls_idx,
    float* __restrict__ out) {
  const int t = threadIdx.x;
  const int sub = t & 31;
  const int idx = blockIdx.x * 8 + (t >> 5);
  const int f = idx % F;
  const int k = (idx / F) % K;
  const int s = idx / (K * F);

  const int p = perm_idx[idx];
  const int c = cls_idx[idx];
  const int rowd = ((s ^ 1) * F + p) * K + c;

  float4 ta = reinterpret_cast<const float4*>(Ta)[(s * K + k) * 32 + sub];
  float4 tv = reinterpret_cast<const float4*>(Tv)[((s * F + f) * K + k) * 32 + sub];
  float4 td = reinterpret_cast<const float4*>(Tv)[rowd * 32 + sub];
  float d1 = 0.f, d2 = 0.f, e;
  e = ta.x - tv.x; d1 += e * e;
  e = ta.y - tv.y; d1 += e * e;
  e = ta.z - tv.z; d1 += e * e;
  e = ta.w - tv.w; d1 += e * e;
  e = ta.x - td.x; d2 += e * e;
  e = ta.y - td.y; d2 += e * e;
  e = ta.z - td.z; d2 += e * e;
  e = ta.w - td.w; d2 += e * e;
#pragma unroll
  for (int m = 16; m >= 1; m >>= 1) {
    d1 += __shfl_xor(d1, m, 64);
    d2 += __shfl_xor(d2, m, 64);
  }
  if (sub == 0) {
    float pa = pred_a[s * K + k];
    bool act = pa > 0.3f;
    int num = (int)floorf(pa * (float)F);
    float pvv = pred_v[(s * F + f) * K + k];
    float sg = 1.0f / (1.0f + expf(-pvv));
    bool mco = act && (sg > 0.3f);
    bool mdi = act && (f < num);
    float lco = d1 * (1.0f / 128.0f);
    float ldi = d2 * (1.0f / 128.0f);
    out[idx] = mco ? lco : 0.0f;
    out[NOUT + idx] = mdi ? ldi : 0.0f;
    out[2 * NOUT + idx] = mco ? 1.0f : 0.0f;
    out[3 * NOUT + idx] = mdi ? 1.0f : 0.0f;
  }
}

extern "C" void kernel_launch(void* const* d_in, const int* in_sizes, int n_in,
                              void* d_out, int out_size, void* d_ws, size_t ws_size,
                              hipStream_t stream) {
  const float* feat_a     = (const float*)d_in[0];
  const float* pred_a     = (const float*)d_in[1];
  const float* feat_v_raw = (const float*)d_in[2];
  const float* pred_v     = (const float*)d_in[3];
  const float* cam        = (const float*)d_in[4];
  const float* W1a = (const float*)d_in[5];
  const float* b1a = (const float*)d_in[6];
  const float* W2a = (const float*)d_in[7];
  const float* b2a = (const float*)d_in[8];
  const float* ga  = (const float*)d_in[9];
  const float* bna = (const float*)d_in[10];
  const float* W1v = (const float*)d_in[11];
  const float* b1v = (const float*)d_in[12];
  const float* W2v = (const float*)d_in[13];
  const float* b2v = (const float*)d_in[14];
  const float* gv  = (const float*)d_in[15];
  const float* bnv = (const float*)d_in[16];
  const int* perm_idx = (const int*)d_in[17];
  const int* cls_idx  = (const int*)d_in[18];
  float* out = (float*)d_out;

  char* w = (char*)d_ws;
  unsigned short* fgb  = (unsigned short*)(w);
  unsigned short* XaB  = (unsigned short*)(w + 4587520);
  unsigned short* W1aT = (unsigned short*)(w + 4587520 + 458752);
  unsigned short* W1vT = (unsigned short*)(w + 4587520 + 458752 + 131072);
  unsigned short* W2aT = (unsigned short*)(w + 4587520 + 458752 + 262144);
  unsigned short* W2vT = (unsigned short*)(w + 4587520 + 458752 + 262144 + 32768);
  float* Ta = (float*)(w + 4587520 + 458752 + 262144 + 65536);
  float* Tv = (float*)(w + 4587520 + 458752 + 262144 + 65536 + 229376);

  fgconv_kernel<<<FG_BLKS + CONV_BLKS, 256, 0, stream>>>(
      feat_v_raw, cam, fgb, feat_a, W1a, W1v, W2a, W2v,
      XaB, W1aT, W1vT, W2aT, W2vT);
  mlp3_kernel<<<MLP_BLK_A + MLP_BLK_V, 256, 0, stream>>>(
      XaB, fgb, W1aT, W2aT, b1a, b2a, ga, bna,
      W1vT, W2vT, b1v, b2v, gv, bnv, Ta, Tv);
  loss_kernel<<<NOUT / 8, 256, 0, stream>>>(Ta, Tv, pred_a, pred_v, perm_idx,
                                            cls_idx, out);
}